// Round 4
// baseline (346.817 us; speedup 1.0000x reference)
//
#include <hip/hip_runtime.h>
#include <hip/hip_bf16.h>
#include <stdint.h>
#include <stddef.h>

typedef __hip_bfloat16 bf16;
typedef __attribute__((ext_vector_type(8))) short bf16x8;
typedef __attribute__((ext_vector_type(4))) float f32x4;

namespace {
constexpr int kB = 32, kC = 256, kH = 56, kW = 56, kOC = 256, kR = 64;
constexpr int kHP = 58, kWP = 58;
constexpr int kPlane = kH * kW;            // 3136
constexpr int kNPix  = kB * kPlane;        // 100352
constexpr int kBM = 256, kBN = 256, kBK = 64;
constexpr int kKT = 9 * (kC / kBK);        // 36 K-tiles
constexpr int kAT = kBM * kBK;             // 16384 elems = 32KB
constexpr int kBTile = kBN * kBK;          // 16384 elems = 32KB
}

// global -> LDS direct load, 16B per lane. lds ptr must be wave-uniform;
// HW writes at lds_base + lane*16. Global src is per-lane.
__device__ __forceinline__ void gload16(const void* g, void* lds_wave_uniform) {
    __builtin_amdgcn_global_load_lds(
        (const __attribute__((address_space(1))) uint32_t*)(uintptr_t)g,
        (__attribute__((address_space(3))) uint32_t*)(uint32_t)(uintptr_t)lds_wave_uniform,
        16, 0, 0);
}

__device__ __forceinline__ unsigned short f2bf(float f) {
    union { float f; unsigned int u; } cv; cv.f = f;
    const unsigned int u = cv.u;
    return (unsigned short)((u + 0x7FFFu + ((u >> 16) & 1u)) >> 16);  // RNE
}

// ---- Kernel A: merge U,V -> Wb[tap][oc][c] (bf16) ----
__global__ void merge_weights(const float* __restrict__ U, const float* __restrict__ V,
                              bf16* __restrict__ Wb) {
    const int tap = blockIdx.x >> 8;   // 0..8
    const int o   = blockIdx.x & 255;
    const int c   = threadIdx.x;       // 0..255
    const float* u = U + (size_t)(tap * kOC + o) * kR;       // U[tap][o][r]
    const float* v = V + (size_t)(tap * kR) * kC + c;        // V[tap][r][c]
    float acc = 0.f;
#pragma unroll
    for (int r = 0; r < kR; ++r) acc += u[r] * v[r * kC];
    Wb[(size_t)(tap * kOC + o) * kC + c] = __float2bfloat16(acc);
}

// ---- Kernel B: NCHW f32 -> padded NHWC bf16 xt[b][58][58][256] ----
__global__ __launch_bounds__(256)
void pad_nhwc(const float* __restrict__ x, bf16* __restrict__ xt) {
    const int b  = blockIdx.x / kHP;
    const int hp = blockIdx.x % kHP;
    const int tid = threadIdx.x;
    bf16* dst = xt + (size_t)(b * kHP + hp) * (kWP * kC);

    if (hp == 0 || hp == kHP - 1) {
        uint4* d4 = (uint4*)dst;
        constexpr int n16 = (kWP * kC * 2) / 16;  // 1856
        for (int i = tid; i < n16; i += 256) d4[i] = uint4{0, 0, 0, 0};
        return;
    }

    const int h = hp - 1;
    __shared__ unsigned short t[256][58];

    const int w4 = tid & 15;
    const int cb = tid >> 4;
#pragma unroll
    for (int pass = 0; pass < 16; ++pass) {
        const int c = pass * 16 + cb;
        if (w4 < 14) {
            const float4 v = *reinterpret_cast<const float4*>(
                x + ((size_t)(b * kC + c) * kH + h) * kW + w4 * 4);
            t[c][w4 * 4 + 0] = f2bf(v.x);
            t[c][w4 * 4 + 1] = f2bf(v.y);
            t[c][w4 * 4 + 2] = f2bf(v.z);
            t[c][w4 * 4 + 3] = f2bf(v.w);
        }
    }
    __syncthreads();

    const int c2   = (tid & 127) * 2;
    const int half = tid >> 7;
    unsigned int* dw = (unsigned int*)dst;
#pragma unroll
    for (int wpi = 0; wpi < 29; ++wpi) {
        const int wp = wpi * 2 + half;
        unsigned int val = 0;
        if (wp >= 1 && wp <= kW) {
            const int w = wp - 1;
            val = (unsigned int)t[c2][w] | ((unsigned int)t[c2 + 1][w] << 16);
        }
        dw[(size_t)wp * 128 + (c2 >> 1)] = val;
    }
}

// ---- Kernel C: implicit GEMM, m201-geometry schedule ----
// M=256(all OC), N tiled 256 pixels, BK=64 (tap-major K: 9 taps x 4 c-steps).
// 8 waves 2Mx4N, wave-tile 128x64; LDS 2x(32+32)KB double-buffer;
// counted vmcnt(8), raw barriers, XOR-swizzled LDS, setprio MFMA clusters.
__global__ __launch_bounds__(512, 1)
void conv_mfma(const bf16* __restrict__ Wb, const bf16* __restrict__ xt,
               float* __restrict__ out) {
    __shared__ bf16 Asm[2 * kAT];      // 64KB
    __shared__ bf16 Bsm[2 * kBTile];   // 64KB

    const int tid  = threadIdx.x;
    const int lane = tid & 63;
    const int wid  = tid >> 6;

    constexpr int nwg = kNPix / kBN;   // 392 = 8*49
    constexpr int cpx = nwg / 8;       // 49
    const int bid = blockIdx.x;
    const int swz = (bid & 7) * cpx + (bid >> 3);
    const int p0  = swz * kBN;

    // ---- staging geometry (linear LDS dest; swizzle applied on SOURCE) ----
    const int l3 = lane >> 3;          // 0..7 == row&7 of this lane's row
    const int l7 = lane & 7;
    const int skoff = (l7 ^ l3) * 8;   // swizzled k offset (elems)

    const bf16* gA[4];
#pragma unroll
    for (int i = 0; i < 4; ++i)
        gA[i] = Wb + (size_t)(wid * 32 + i * 8 + l3) * kC + skoff;

    const bf16* gB[4];
#pragma unroll
    for (int i = 0; i < 4; ++i) {
        const int gp = p0 + wid * 32 + i * 8 + l3;
        const int bb = gp / kPlane, q = gp - bb * kPlane;
        const int hh = q / kW, ww = q - hh * kW;
        gB[i] = xt + ((size_t)((bb * kHP + hh) * kWP + ww)) * kC + skoff;
    }

    auto stage = [&](int t, int buf) {
        const int tap = t >> 2;
        const int c0  = (t & 3) * kBK;
        const size_t aoff = (size_t)tap * (kOC * kC) + c0;
        const size_t boff = (size_t)((tap / 3) * kWP + (tap % 3)) * kC + c0;
        char* Ad = (char*)(Asm + buf * kAT) + wid * 4096;
        char* Bd = (char*)(Bsm + buf * kBTile) + wid * 4096;
#pragma unroll
        for (int i = 0; i < 4; ++i) gload16(gA[i] + aoff, Ad + i * 1024);
#pragma unroll
        for (int i = 0; i < 4; ++i) gload16(gB[i] + boff, Bd + i * 1024);
    };

    // ---- fragment-read geometry (swizzled) ----
    const int wr   = wid >> 2;         // 0..1 : 128 oc rows
    const int wcn  = wid & 3;          // 0..3 : 64 pixel cols
    const int lrow = lane & 15;
    const int qt   = lane >> 4;
    const int ck[2] = { (qt ^ (lrow & 7)) * 8, ((4 | qt) ^ (lrow & 7)) * 8 };

    f32x4 acc[8][4] = {};

    stage(0, 0);
    for (int t = 0; t < kKT; ++t) {
        const int buf = t & 1;
        if (t + 1 < kKT) {
            stage(t + 1, buf ^ 1);                               // prefetch
            asm volatile("s_waitcnt vmcnt(8)" ::: "memory");     // tile t landed
        } else {
            asm volatile("s_waitcnt vmcnt(0)" ::: "memory");
        }
        __builtin_amdgcn_s_barrier();

        const bf16* Ac = Asm + buf * kAT;
        const bf16* Bc = Bsm + buf * kBTile;

        bf16x8 bfr[4][2];
#pragma unroll
        for (int nj = 0; nj < 4; ++nj)
#pragma unroll
            for (int ko = 0; ko < 2; ++ko)
                bfr[nj][ko] = *(const bf16x8*)(Bc + (wcn * 64 + nj * 16 + lrow) * kBK + ck[ko]);

#pragma unroll
        for (int mh = 0; mh < 2; ++mh) {
            bf16x8 af[4][2];
#pragma unroll
            for (int mi = 0; mi < 4; ++mi)
#pragma unroll
                for (int ko = 0; ko < 2; ++ko)
                    af[mi][ko] = *(const bf16x8*)(Ac + (wr * 128 + mh * 64 + mi * 16 + lrow) * kBK + ck[ko]);
            __builtin_amdgcn_s_setprio(1);
#pragma unroll
            for (int mi = 0; mi < 4; ++mi)
#pragma unroll
                for (int nj = 0; nj < 4; ++nj)
#pragma unroll
                    for (int ko = 0; ko < 2; ++ko)
                        acc[mh * 4 + mi][nj] = __builtin_amdgcn_mfma_f32_16x16x32_bf16(
                            af[mi][ko], bfr[nj][ko], acc[mh * 4 + mi][nj], 0, 0, 0);
            __builtin_amdgcn_s_setprio(0);
        }

        asm volatile("s_waitcnt lgkmcnt(0)" ::: "memory");  // my ds_reads done
        __builtin_amdgcn_s_barrier();                       // all waves done -> buf reusable
    }

    // ---- epilogue: C/D layout col(pixel)=lane&15, row(oc)=(lane>>4)*4+reg ----
#pragma unroll
    for (int nj = 0; nj < 4; ++nj) {
        const int gp = p0 + wcn * 64 + nj * 16 + lrow;
        const int bb = gp / kPlane;
        const int qq = gp - bb * kPlane;
        float* ob = out + (size_t)bb * (kOC * kPlane) + qq;
#pragma unroll
        for (int mi8 = 0; mi8 < 8; ++mi8) {
            const int o = wr * 128 + mi8 * 16 + qt * 4;
            float* op = ob + (size_t)o * kPlane;
#pragma unroll
            for (int r = 0; r < 4; ++r)
                op[(size_t)r * kPlane] = acc[mi8][nj][r];
        }
    }
}

extern "C" void kernel_launch(void* const* d_in, const int* in_sizes, int n_in,
                              void* d_out, int out_size, void* d_ws, size_t ws_size,
                              hipStream_t stream) {
    const float* x = (const float*)d_in[0];
    const float* U = (const float*)d_in[1];
    const float* V = (const float*)d_in[2];
    float* out = (float*)d_out;

    bf16* Wb = (bf16*)d_ws;                                     // 1.18 MB
    bf16* xt = (bf16*)((char*)d_ws + (size_t)9 * kOC * kC * 2); // 55 MB

    merge_weights<<<dim3(9 * kOC), dim3(kC), 0, stream>>>(U, V, Wb);
    pad_nhwc<<<dim3(kB * kHP), dim3(256), 0, stream>>>(x, xt);
    conv_mfma<<<dim3(kNPix / kBN), dim3(512), 0, stream>>>(Wb, xt, out);
}